// Round 9
// baseline (304.009 us; speedup 1.0000x reference)
//
#include <hip/hip_runtime.h>
#include <hip/hip_fp16.h>

typedef __attribute__((ext_vector_type(8))) _Float16 f16x8;
typedef __attribute__((ext_vector_type(4))) float f32x4;
typedef __attribute__((ext_vector_type(16))) float f32x16;

#define M_DIM 8192
#define N_DIM 4096
#define K_DIM 4096
#define BM 256
#define BN 256
#define BK 64
#define NT (K_DIM / BK)      // 64 K-tiles
#define ITERS (NT / 2)       // 32 iterations, 2 tiles each

__constant__ float FP4_LUT[16] = {0.f, 0.5f, 1.f, 1.5f, 2.f, 3.f, 4.f, 6.f,
                                  -0.f, -0.5f, -1.f, -1.5f, -2.f, -3.f, -4.f, -6.f};

__device__ inline void glds16(const void* g, void* l) {
    __builtin_amdgcn_global_load_lds(
        (const __attribute__((address_space(1))) void*)g,
        (__attribute__((address_space(3))) void*)l, 16, 0, 0);
}

// ---- prepass 1: x fp32 -> fp16 ----
__global__ __launch_bounds__(256) void cvt_x_kernel(const float* __restrict__ x,
                                                    _Float16* __restrict__ xh) {
    int i = (blockIdx.x * 256 + threadIdx.x) * 8;
    const float4* p = (const float4*)(x + i);
    float4 a = p[0], b = p[1];
    f16x8 h;
    h[0] = (_Float16)a.x; h[1] = (_Float16)a.y;
    h[2] = (_Float16)a.z; h[3] = (_Float16)a.w;
    h[4] = (_Float16)b.x; h[5] = (_Float16)b.y;
    h[6] = (_Float16)b.z; h[7] = (_Float16)b.w;
    *(f16x8*)(xh + i) = h;
}

// ---- prepass 2: packed fp4 bytes -> fp16 W[N][K] row-major ----
__global__ __launch_bounds__(256) void dequant_w_kernel(const int* __restrict__ w,
                                                        const float* __restrict__ wsc,
                                                        _Float16* __restrict__ wh) {
    int t = blockIdx.x * 256 + threadIdx.x;
    int4 b4 = ((const int4*)w)[t];
    int o  = t >> 9;
    int j0 = (t & 511) << 2;
    float s = wsc[(o << 8) + (j0 >> 3)];
    f16x8 h;
    int b;
    b = b4.x; h[0] = (_Float16)(FP4_LUT[(b >> 4) & 15] * s); h[1] = (_Float16)(FP4_LUT[b & 15] * s);
    b = b4.y; h[2] = (_Float16)(FP4_LUT[(b >> 4) & 15] * s); h[3] = (_Float16)(FP4_LUT[b & 15] * s);
    b = b4.z; h[4] = (_Float16)(FP4_LUT[(b >> 4) & 15] * s); h[5] = (_Float16)(FP4_LUT[b & 15] * s);
    b = b4.w; h[6] = (_Float16)(FP4_LUT[(b >> 4) & 15] * s); h[7] = (_Float16)(FP4_LUT[b & 15] * s);
    *(f16x8*)(wh + ((long)o << 12) + (j0 << 1)) = h;
}

// ======== 8-phase 256x256 GEMM, register-prefetch pipeline, 32x32x16 MFMA ========
// r9: shape switch 16x16x32 -> 32x32x16 (ceiling 2382 vs 2075 TF; 8 MFMA/phase
// instead of 16; identical LDS traffic). Fragment: lane = row + 32*khalf, holds
// k = khalf*8 + j. Same XOR swizzle slot^=(row>>1)&3 -> exactly 8 lanes per
// 16B bank-span = wave64-b128 minimum, 0 conflicts.
// Pipeline (r8): phase = {stage glds | prefetch next phase's frags | lgkm(4|8)
// retiring prev phase's reads | 8 MFMA on prev-phase regs | [vmcnt(6) even] |
// one barrier}. Square XCD chunks (r7). Counted vmcnt throughout (T4).

#define VM6 asm volatile("s_waitcnt vmcnt(6)" ::: "memory")
#define VM4 asm volatile("s_waitcnt vmcnt(4)" ::: "memory")
#define VM2 asm volatile("s_waitcnt vmcnt(2)" ::: "memory")
#define VM0 asm volatile("s_waitcnt vmcnt(0)" ::: "memory")
#define LG8 asm volatile("s_waitcnt lgkmcnt(8)" ::: "memory")
#define LG4 asm volatile("s_waitcnt lgkmcnt(4)" ::: "memory")
#define LG0 asm volatile("s_waitcnt lgkmcnt(0)" ::: "memory")
#define NOP ((void)0)

#define STAGE(OP, SD, KH, KOFF) do {                                           \
    _Float16* _d = lds + (SD)*32768 + (OP)*16384 + (KH)*8192 + (wid << 9);     \
    const _Float16* _s = ((OP) ? srcB : srcA) + (KOFF);                        \
    glds16(_s, _d);                                                            \
    glds16(_s + (size_t)128 * K_DIM, _d + 4096);                               \
  } while (0)

// DOAF/DOBF: prefetch next phase's A/B frags. AFN/BFN index = [sub*2 + kstep].
// LGW retires exactly the previous phase's reads (leaves this phase's in flight).
#define PH(DOAF, NCB, NKH, NMH, AFN, DOBF, BFN, LGW, MHC, AFC, BFC, STG, VMW) do { \
    STG;                                                                       \
    const _Float16* _nb = lds + (NCB)*32768 + (NKH)*8192;                      \
    if (DOAF) {                                                                \
      AFN[0] = *(const f16x8*)(_nb + aBase + (NMH)*2048 + aS0);                \
      AFN[1] = *(const f16x8*)(_nb + aBase + (NMH)*2048 + aS1);                \
      AFN[2] = *(const f16x8*)(_nb + aBase + (NMH)*2048 + 1024 + aS0);         \
      AFN[3] = *(const f16x8*)(_nb + aBase + (NMH)*2048 + 1024 + aS1);         \
    }                                                                          \
    if (DOBF) {                                                                \
      BFN[0] = *(const f16x8*)(_nb + bBase + aS0);                             \
      BFN[1] = *(const f16x8*)(_nb + bBase + aS1);                             \
      BFN[2] = *(const f16x8*)(_nb + bBase + 1024 + aS0);                      \
      BFN[3] = *(const f16x8*)(_nb + bBase + 1024 + aS1);                      \
    }                                                                          \
    LGW;                                                                       \
    __builtin_amdgcn_s_setprio(1);                                             \
    _Pragma("unroll")                                                          \
    for (int ks = 0; ks < 2; ++ks)                                             \
      _Pragma("unroll")                                                        \
      for (int ms = 0; ms < 2; ++ms)                                           \
        _Pragma("unroll")                                                      \
        for (int ns = 0; ns < 2; ++ns)                                         \
          acc[(MHC)*2 + ms][ns] = __builtin_amdgcn_mfma_f32_32x32x16_f16(      \
              AFC[ms*2+ks], BFC[ns*2+ks], acc[(MHC)*2 + ms][ns], 0, 0, 0);     \
    __builtin_amdgcn_s_setprio(0);                                             \
    VMW;                                                                       \
    __builtin_amdgcn_s_barrier();                                              \
  } while (0)

__global__ __launch_bounds__(512, 2) void gemm_f16_pf(const _Float16* __restrict__ A,
                                                      const _Float16* __restrict__ B,
                                                      const float* __restrict__ bias,
                                                      float* __restrict__ C) {
    __shared__ _Float16 lds[2 * 32768];   // 128 KiB

    const int tid  = threadIdx.x;
    const int wid  = tid >> 6;
    const int lane = tid & 63;
    const int l31  = lane & 31;     // row (A) / col (B) within 32x32 frag
    const int hh   = lane >> 5;     // k-half: k = hh*8 + j
    const int g    = (lane >> 1) & 3;   // swizzle group = (row>>1)&3
    const int wm   = wid >> 2;      // 0..1
    const int wn   = wid & 3;       // 0..3

    // square XCD chunks: 8bm x 8bn per XCD (r7: FETCH 650->198 MB)
    const int c = blockIdx.x & 7;
    const int q = blockIdx.x >> 3;           // 0..63
    const int bm = (c >> 1) * 8 + (q & 7);   // 0..31
    const int bn = (c & 1) * 8 + (q >> 3);   // 0..15
    const int brow = bm * BM;
    const int bcol = bn * BN;

    // staging source: row tid>>2; pre-swizzled col slot (rule #21)
    const int s_col = (((tid & 3) ^ ((tid >> 3) & 3)) << 3);
    const _Float16* srcA = A + (size_t)(brow + (tid >> 2)) * K_DIM + s_col;
    const _Float16* srcB = B + (size_t)(bcol + (tid >> 2)) * K_DIM + s_col;

    // ds_read offsets (f16 units). Row r holds logical slot s at LDS slot s^g.
    // kstep slot: logical = (kstep<<1)|hh -> stored = ((kstep<<1)|hh)^g.
    const int aS0 = ((hh ^ g)) << 3;         // kstep 0, *8 f16
    const int aS1 = (((2 | hh) ^ g)) << 3;   // kstep 1
    const int aBase = (wm * 128 + l31) * 32;
    const int bBase = 16384 + (wn * 64 + l31) * 32;

    f16x8 af0[4], af1[4], bf0[4], bf1[4];
    f32x16 acc[4][2] = {};

    // prologue: stage buf0 (t0 full) then buf1.kh0 (t1); retire all but last 2
    STAGE(0, 0, 0, 0);
    STAGE(1, 0, 0, 0);
    STAGE(0, 0, 1, 32);
    STAGE(1, 0, 1, 32);
    STAGE(0, 1, 0, 64);
    STAGE(1, 1, 0, 64);
    VM2;
    __builtin_amdgcn_s_barrier();
    // prefetch phase-0 operands: buf0.kh0, m-half 0 + B
    af0[0] = *(const f16x8*)(lds + aBase + aS0);
    af0[1] = *(const f16x8*)(lds + aBase + aS1);
    af0[2] = *(const f16x8*)(lds + aBase + 1024 + aS0);
    af0[3] = *(const f16x8*)(lds + aBase + 1024 + aS1);
    bf0[0] = *(const f16x8*)(lds + bBase + aS0);
    bf0[1] = *(const f16x8*)(lds + bBase + aS1);
    bf0[2] = *(const f16x8*)(lds + bBase + 1024 + aS0);
    bf0[3] = *(const f16x8*)(lds + bBase + 1024 + aS1);

    for (int i = 0; i < ITERS - 1; ++i) {
        const int kb = i << 7;
        PH(1, 0,0,1, af1, 0,bf0, LG4, 0, af0, bf0, STAGE(0,1,1,kb+96),  VM6); // p0
        PH(1, 0,1,0, af0, 1,bf1, LG8, 1, af1, bf0, STAGE(1,1,1,kb+96),  NOP); // p1
        PH(1, 0,1,1, af1, 0,bf0, LG4, 0, af0, bf1, STAGE(0,0,0,kb+128), VM6); // p2
        PH(1, 1,0,0, af0, 1,bf0, LG8, 1, af1, bf1, STAGE(1,0,0,kb+128), NOP); // p3
        PH(1, 1,0,1, af1, 0,bf0, LG4, 0, af0, bf0, STAGE(0,0,1,kb+160), VM6); // p4
        PH(1, 1,1,0, af0, 1,bf1, LG8, 1, af1, bf0, STAGE(1,0,1,kb+160), NOP); // p5
        PH(1, 1,1,1, af1, 0,bf0, LG4, 0, af0, bf1, STAGE(0,1,0,kb+192), VM6); // p6
        PH(1, 0,0,0, af0, 1,bf0, LG8, 1, af1, bf1, STAGE(1,1,0,kb+192), NOP); // p7
    }
    {   // drain iteration (tiles NT-2, NT-1): only t+1.kh1 staging remains
        const int kb = (ITERS - 1) << 7;
        PH(1, 0,0,1, af1, 0,bf0, LG4, 0, af0, bf0, STAGE(0,1,1,kb+96), VM6);  // p0
        PH(1, 0,1,0, af0, 1,bf1, LG8, 1, af1, bf0, STAGE(1,1,1,kb+96), NOP);  // p1
        PH(1, 0,1,1, af1, 0,bf0, LG4, 0, af0, bf1, NOP,                VM4);  // p2
        PH(1, 1,0,0, af0, 1,bf0, LG8, 1, af1, bf1, NOP,                NOP);  // p3
        PH(1, 1,0,1, af1, 0,bf0, LG4, 0, af0, bf0, NOP,                VM0);  // p4
        PH(1, 1,1,0, af0, 1,bf1, LG8, 1, af1, bf0, NOP,                NOP);  // p5
        PH(1, 1,1,1, af1, 0,bf0, LG4, 0, af0, bf1, NOP,                NOP);  // p6
        PH(0, 0,0,0, af0, 0,bf0, LG0, 1, af1, bf1, NOP,                NOP);  // p7
    }

    // epilogue: 32x32 C/D layout: col = lane&31, row = (reg&3) + 8*(reg>>2) + 4*hh
#pragma unroll
    for (int mi = 0; mi < 4; ++mi) {
        int rbase = brow + wm * 128 + mi * 32 + 4 * hh;
#pragma unroll
        for (int ni = 0; ni < 2; ++ni) {
            int col = bcol + wn * 64 + ni * 32 + l31;
            float bv = bias[col];
#pragma unroll
            for (int j = 0; j < 16; ++j) {
                int row = rbase + (j & 3) + 8 * (j >> 2);
                C[(size_t)row * N_DIM + col] = acc[mi][ni][j] + bv;
            }
        }
    }
}

// ---- fallback (only if ws too small) ----
__global__ __launch_bounds__(256) void fallback_kernel(const float* __restrict__ x,
                                                       const int* __restrict__ w,
                                                       const float* __restrict__ wsc,
                                                       const float* __restrict__ bias,
                                                       float* __restrict__ out) {
    long idx = (long)blockIdx.x * 256 + threadIdx.x;
    int t = (int)(idx >> 12);
    int o = (int)(idx & 4095);
    float acc = 0.f;
    for (int j = 0; j < K_DIM / 2; ++j) {
        int b = w[o * (K_DIM / 2) + j];
        float s = wsc[(o << 8) + (j >> 3)];
        acc += x[(long)t * K_DIM + 2 * j]     * (FP4_LUT[(b >> 4) & 15] * s);
        acc += x[(long)t * K_DIM + 2 * j + 1] * (FP4_LUT[b & 15] * s);
    }
    out[idx] = acc + bias[o];
}

extern "C" void kernel_launch(void* const* d_in, const int* in_sizes, int n_in,
                              void* d_out, int out_size, void* d_ws, size_t ws_size,
                              hipStream_t stream) {
    const float* x    = (const float*)d_in[0];
    const int*   w    = (const int*)d_in[1];
    const float* wsc  = (const float*)d_in[2];
    const float* bias = (const float*)d_in[3];
    float* out = (float*)d_out;

    const size_t xh_bytes = (size_t)M_DIM * K_DIM * 2;   // 64 MB
    const size_t wh_bytes = (size_t)N_DIM * K_DIM * 2;   // 32 MB

    if (ws_size >= xh_bytes + wh_bytes) {
        _Float16* xh = (_Float16*)d_ws;
        _Float16* wh = (_Float16*)((char*)d_ws + xh_bytes);
        cvt_x_kernel<<<(M_DIM * K_DIM) / (256 * 8), 256, 0, stream>>>(x, xh);
        dequant_w_kernel<<<(N_DIM * (K_DIM / 2)) / (256 * 4), 256, 0, stream>>>(w, wsc, wh);
        gemm_f16_pf<<<(M_DIM / BM) * (N_DIM / BN), 512, 0, stream>>>(xh, wh, bias, out);
    } else {
        fallback_kernel<<<((long)M_DIM * N_DIM) / 256, 256, 0, stream>>>(x, w, wsc, bias, out);
    }
}

// Round 10
// 279.455 us; speedup vs baseline: 1.0879x; 1.0879x over previous
//
#include <hip/hip_runtime.h>
#include <hip/hip_fp16.h>

typedef __attribute__((ext_vector_type(8))) _Float16 f16x8;
typedef __attribute__((ext_vector_type(4))) float f32x4;

#define M_DIM 8192
#define N_DIM 4096
#define K_DIM 4096
#define BM 256
#define BN 256
#define BK 64
#define NT (K_DIM / BK)      // 64 K-tiles
#define ITERS (NT / 2)       // 32 iterations, 2 tiles each

__constant__ float FP4_LUT[16] = {0.f, 0.5f, 1.f, 1.5f, 2.f, 3.f, 4.f, 6.f,
                                  -0.f, -0.5f, -1.f, -1.5f, -2.f, -3.f, -4.f, -6.f};

__device__ inline void glds16(const void* g, void* l) {
    __builtin_amdgcn_global_load_lds(
        (const __attribute__((address_space(1))) void*)g,
        (__attribute__((address_space(3))) void*)l, 16, 0, 0);
}

// ---- prepass 1: x fp32 -> fp16 ----
__global__ __launch_bounds__(256) void cvt_x_kernel(const float* __restrict__ x,
                                                    _Float16* __restrict__ xh) {
    int i = (blockIdx.x * 256 + threadIdx.x) * 8;
    const float4* p = (const float4*)(x + i);
    float4 a = p[0], b = p[1];
    f16x8 h;
    h[0] = (_Float16)a.x; h[1] = (_Float16)a.y;
    h[2] = (_Float16)a.z; h[3] = (_Float16)a.w;
    h[4] = (_Float16)b.x; h[5] = (_Float16)b.y;
    h[6] = (_Float16)b.z; h[7] = (_Float16)b.w;
    *(f16x8*)(xh + i) = h;
}

// ---- prepass 2: packed fp4 bytes -> fp16 W[N][K] row-major ----
__global__ __launch_bounds__(256) void dequant_w_kernel(const int* __restrict__ w,
                                                        const float* __restrict__ wsc,
                                                        _Float16* __restrict__ wh) {
    int t = blockIdx.x * 256 + threadIdx.x;
    int4 b4 = ((const int4*)w)[t];
    int o  = t >> 9;
    int j0 = (t & 511) << 2;
    float s = wsc[(o << 8) + (j0 >> 3)];
    f16x8 h;
    int b;
    b = b4.x; h[0] = (_Float16)(FP4_LUT[(b >> 4) & 15] * s); h[1] = (_Float16)(FP4_LUT[b & 15] * s);
    b = b4.y; h[2] = (_Float16)(FP4_LUT[(b >> 4) & 15] * s); h[3] = (_Float16)(FP4_LUT[b & 15] * s);
    b = b4.z; h[4] = (_Float16)(FP4_LUT[(b >> 4) & 15] * s); h[5] = (_Float16)(FP4_LUT[b & 15] * s);
    b = b4.w; h[6] = (_Float16)(FP4_LUT[(b >> 4) & 15] * s); h[7] = (_Float16)(FP4_LUT[b & 15] * s);
    *(f16x8*)(wh + ((long)o << 12) + (j0 << 1)) = h;
}

// ====== 8-phase 256x256 GEMM, register-prefetch + half-barrier pipeline (r10) ======
// r10 = r8 (16x16x32, reg-prefetch, 0-conflict XOR swizzle, square XCD chunks)
// with barriers removed from EVEN phases (4/iter). Counted waits re-derived:
//   VM4 at each odd phase before its barrier: retires stages >=2 phases old.
//     RAW min distance stage@p -> read@p+4: retired by VM4@(p+2|p+3 odd),
//     published by that barrier, read >=1 barrier later.  (drain: VM4,VM0)
//   LG4/LG8 unchanged: a wave's ds_reads retire <=1 phase after issue, before
//     its next odd barrier => WAR (read@p, restage@p+2) sealed by that barrier.
// Waves may skew +-2 phases between barriers: one wave's read-burst overlaps
// another's MFMA-burst -> LDS pipe and matrix pipe run concurrently.

#define VM4 asm volatile("s_waitcnt vmcnt(4)" ::: "memory")
#define VM0 asm volatile("s_waitcnt vmcnt(0)" ::: "memory")
#define LG8 asm volatile("s_waitcnt lgkmcnt(8)" ::: "memory")
#define LG4 asm volatile("s_waitcnt lgkmcnt(4)" ::: "memory")
#define LG0 asm volatile("s_waitcnt lgkmcnt(0)" ::: "memory")
#define NOP ((void)0)

#define STAGE(OP, SD, KH, KOFF) do {                                           \
    _Float16* _d = lds + (SD)*32768 + (OP)*16384 + (KH)*8192 + (wid << 9);     \
    const _Float16* _s = ((OP) ? srcB : srcA) + (KOFF);                        \
    glds16(_s, _d);                                                            \
    glds16(_s + (size_t)128 * K_DIM, _d + 4096);                               \
  } while (0)

// Phase: stage | prefetch next-phase frags | LG retiring prev-phase reads |
// 16 MFMA on prev-phase regs | VMW | [barrier if BAR]
#define PH(DOAF, NCB, NKH, NMH, AFN, DOBF, BFN, LGW, MHC, AFC, BFC, STG, VMW, BAR) do { \
    STG;                                                                       \
    const _Float16* _nb = lds + (NCB)*32768 + (NKH)*8192;                      \
    if (DOAF) {                                                                \
      AFN[0] = *(const f16x8*)(_nb + a_off + (NMH)*2048);                      \
      AFN[1] = *(const f16x8*)(_nb + a_off + (NMH)*2048 + 512);                \
      AFN[2] = *(const f16x8*)(_nb + a_off + (NMH)*2048 + 1024);               \
      AFN[3] = *(const f16x8*)(_nb + a_off + (NMH)*2048 + 1536);               \
    }                                                                          \
    if (DOBF) {                                                                \
      BFN[0] = *(const f16x8*)(_nb + b_off);                                   \
      BFN[1] = *(const f16x8*)(_nb + b_off + 512);                             \
      BFN[2] = *(const f16x8*)(_nb + b_off + 1024);                            \
      BFN[3] = *(const f16x8*)(_nb + b_off + 1536);                            \
    }                                                                          \
    LGW;                                                                       \
    __builtin_amdgcn_s_setprio(1);                                             \
    _Pragma("unroll")                                                          \
    for (int mf = 0; mf < 4; ++mf) {                                           \
      _Pragma("unroll")                                                        \
      for (int nf = 0; nf < 4; ++nf)                                           \
        acc[(MHC)*4 + mf][nf] = __builtin_amdgcn_mfma_f32_16x16x32_f16(        \
            AFC[mf], BFC[nf], acc[(MHC)*4 + mf][nf], 0, 0, 0);                 \
    }                                                                          \
    __builtin_amdgcn_s_setprio(0);                                             \
    VMW;                                                                       \
    if (BAR) __builtin_amdgcn_s_barrier();                                     \
  } while (0)

__global__ __launch_bounds__(512, 2) void gemm_f16_pf(const _Float16* __restrict__ A,
                                                      const _Float16* __restrict__ B,
                                                      const float* __restrict__ bias,
                                                      float* __restrict__ C) {
    __shared__ _Float16 lds[2 * 32768];   // 128 KiB

    const int tid  = threadIdx.x;
    const int wid  = tid >> 6;
    const int lane = tid & 63;
    const int fr   = lane & 15;
    const int kg   = lane >> 4;
    const int wm   = wid >> 2;     // 0..1
    const int wn   = wid & 3;      // 0..3

    // square XCD chunks: 8bm x 8bn per XCD (r7: FETCH 650->198 MB)
    const int c = blockIdx.x & 7;
    const int q = blockIdx.x >> 3;           // 0..63
    const int bm = (c >> 1) * 8 + (q & 7);   // 0..31
    const int bn = (c & 1) * 8 + (q >> 3);   // 0..15
    const int brow = bm * BM;
    const int bcol = bn * BN;

    // staging source: row tid>>2; pre-swizzled col slot (rule #21)
    const int s_col = (((tid & 3) ^ ((tid >> 3) & 3)) << 3);
    const _Float16* srcA = A + (size_t)(brow + (tid >> 2)) * K_DIM + s_col;
    const _Float16* srcB = B + (size_t)(bcol + (tid >> 2)) * K_DIM + s_col;

    // ds_read offsets: row*32 + swizzled 16B slot
    const int swz   = ((kg ^ ((fr >> 1) & 3)) << 3);
    const int a_off = (wm * 128 + fr) * 32 + swz;
    const int b_off = 16384 + (wn * 64 + fr) * 32 + swz;

    f16x8 af0[4], af1[4], bf0[4], bf1[4];
    f32x4 acc[8][4] = {};

    // prologue: 6 stage units; VM4 retires units 1-4 (buf0 complete).
    // buf1.kh0 (units 5,6) retired by VM4@p1 before its p3 readers.
    STAGE(0, 0, 0, 0);
    STAGE(1, 0, 0, 0);
    STAGE(0, 0, 1, 32);
    STAGE(1, 0, 1, 32);
    STAGE(0, 1, 0, 64);
    STAGE(1, 1, 0, 64);
    VM4;
    __builtin_amdgcn_s_barrier();
    // prefetch phase-0 operands: buf0.kh0, m-half 0 + B
    af0[0] = *(const f16x8*)(lds + a_off);
    af0[1] = *(const f16x8*)(lds + a_off + 512);
    af0[2] = *(const f16x8*)(lds + a_off + 1024);
    af0[3] = *(const f16x8*)(lds + a_off + 1536);
    bf0[0] = *(const f16x8*)(lds + b_off);
    bf0[1] = *(const f16x8*)(lds + b_off + 512);
    bf0[2] = *(const f16x8*)(lds + b_off + 1024);
    bf0[3] = *(const f16x8*)(lds + b_off + 1536);

    for (int i = 0; i < ITERS - 1; ++i) {
        const int kb = i << 7;
        PH(1, 0,0,1, af1, 0,bf0, LG4, 0, af0, bf0, STAGE(0,1,1,kb+96),  NOP, 0); // p0
        PH(1, 0,1,0, af0, 1,bf1, LG8, 1, af1, bf0, STAGE(1,1,1,kb+96),  VM4, 1); // p1
        PH(1, 0,1,1, af1, 0,bf0, LG4, 0, af0, bf1, STAGE(0,0,0,kb+128), NOP, 0); // p2
        PH(1, 1,0,0, af0, 1,bf0, LG8, 1, af1, bf1, STAGE(1,0,0,kb+128), VM4, 1); // p3
        PH(1, 1,0,1, af1, 0,bf0, LG4, 0, af0, bf0, STAGE(0,0,1,kb+160), NOP, 0); // p4
        PH(1, 1,1,0, af0, 1,bf1, LG8, 1, af1, bf0, STAGE(1,0,1,kb+160), VM4, 1); // p5
        PH(1, 1,1,1, af1, 0,bf0, LG4, 0, af0, bf1, STAGE(0,1,0,kb+192), NOP, 0); // p6
        PH(1, 0,0,0, af0, 1,bf0, LG8, 1, af1, bf1, STAGE(1,1,0,kb+192), VM4, 1); // p7
    }
    {   // drain iteration (tiles NT-2, NT-1): only t+1.kh1 staging remains
        const int kb = (ITERS - 1) << 7;
        PH(1, 0,0,1, af1, 0,bf0, LG4, 0, af0, bf0, STAGE(0,1,1,kb+96), NOP, 0); // p0
        PH(1, 0,1,0, af0, 1,bf1, LG8, 1, af1, bf0, STAGE(1,1,1,kb+96), VM4, 1); // p1
        PH(1, 0,1,1, af1, 0,bf0, LG4, 0, af0, bf1, NOP,                NOP, 0); // p2
        PH(1, 1,0,0, af0, 1,bf0, LG8, 1, af1, bf1, NOP,                VM0, 1); // p3
        PH(1, 1,0,1, af1, 0,bf0, LG4, 0, af0, bf0, NOP,                NOP, 0); // p4
        PH(1, 1,1,0, af0, 1,bf1, LG8, 1, af1, bf0, NOP,                NOP, 1); // p5
        PH(1, 1,1,1, af1, 0,bf0, LG4, 0, af0, bf1, NOP,                NOP, 0); // p6
        PH(0, 0,0,0, af0, 0,bf0, LG0, 1, af1, bf1, NOP,                NOP, 0); // p7
    }

    // epilogue: C/D layout col = lane&15, row = (lane>>4)*4 + reg
#pragma unroll
    for (int m = 0; m < 8; ++m) {
        int row = brow + wm * 128 + m * 16 + kg * 4;
#pragma unroll
        for (int n = 0; n < 4; ++n) {
            int col = bcol + wn * 64 + n * 16 + fr;
            float bv = bias[col];
#pragma unroll
            for (int j = 0; j < 4; ++j)
                C[(size_t)(row + j) * N_DIM + col] = acc[m][n][j] + bv;
        }
    }
}

// ---- fallback (only if ws too small) ----
__global__ __launch_bounds__(256) void fallback_kernel(const float* __restrict__ x,
                                                       const int* __restrict__ w,
                                                       const float* __restrict__ wsc,
                                                       const float* __restrict__ bias,
                                                       float* __restrict__ out) {
    long idx = (long)blockIdx.x * 256 + threadIdx.x;
    int t = (int)(idx >> 12);
    int o = (int)(idx & 4095);
    float acc = 0.f;
    for (int j = 0; j < K_DIM / 2; ++j) {
        int b = w[o * (K_DIM / 2) + j];
        float s = wsc[(o << 8) + (j >> 3)];
        acc += x[(long)t * K_DIM + 2 * j]     * (FP4_LUT[(b >> 4) & 15] * s);
        acc += x[(long)t * K_DIM + 2 * j + 1] * (FP4_LUT[b & 15] * s);
    }
    out[idx] = acc + bias[o];
}

extern "C" void kernel_launch(void* const* d_in, const int* in_sizes, int n_in,
                              void* d_out, int out_size, void* d_ws, size_t ws_size,
                              hipStream_t stream) {
    const float* x    = (const float*)d_in[0];
    const int*   w    = (const int*)d_in[1];
    const float* wsc  = (const float*)d_in[2];
    const float* bias = (const float*)d_in[3];
    float* out = (float*)d_out;

    const size_t xh_bytes = (size_t)M_DIM * K_DIM * 2;   // 64 MB
    const size_t wh_bytes = (size_t)N_DIM * K_DIM * 2;   // 32 MB

    if (ws_size >= xh_bytes + wh_bytes) {
        _Float16* xh = (_Float16*)d_ws;
        _Float16* wh = (_Float16*)((char*)d_ws + xh_bytes);
        cvt_x_kernel<<<(M_DIM * K_DIM) / (256 * 8), 256, 0, stream>>>(x, xh);
        dequant_w_kernel<<<(N_DIM * (K_DIM / 2)) / (256 * 4), 256, 0, stream>>>(w, wsc, wh);
        gemm_f16_pf<<<(M_DIM / BM) * (N_DIM / BN), 512, 0, stream>>>(xh, wh, bias, out);
    } else {
        fallback_kernel<<<((long)M_DIM * N_DIM) / 256, 256, 0, stream>>>(x, w, wsc, bias, out);
    }
}